// Round 16
// baseline (163.649 us; speedup 1.0000x reference)
//
#include <hip/hip_runtime.h>
#include <hip/hip_bf16.h>
#include <stdint.h>

#define CCH 256
#define NPIX 4096      // 64*64
#define NH 8
#define M2 2560        // K*2*S
#define LOG2E 1.44269504088896f

typedef __attribute__((ext_vector_type(8))) short short8;
typedef __attribute__((ext_vector_type(4))) float f32x4;

__device__ __forceinline__ uint16_t f2bfu(float f) {
    uint32_t u = __builtin_bit_cast(uint32_t, f);
    return (uint16_t)((u + 0x7FFFu + ((u >> 16) & 1u)) >> 16);   // RNE
}
__device__ __forceinline__ uint32_t pack_bf2(float a, float b) {
    return (uint32_t)f2bfu(a) | ((uint32_t)f2bfu(b) << 16);
}
__device__ __forceinline__ short8 u4_to_s8(uint4 v) {
    return __builtin_bit_cast(short8, v);
}
__device__ __forceinline__ short8 mk8(uint32_t a, uint32_t b, uint32_t c, uint32_t d) {
    union { uint32_t u[4]; short8 s; } t;
    t.u[0] = a; t.u[1] = b; t.u[2] = c; t.u[3] = d;
    return t.s;
}

__device__ __forceinline__ void prep_w_one(const float* __restrict__ w, uint16_t* __restrict__ Wk,
                                           int idx, int Cin, int Cout, int K2) {
    int kk = idx & 31;
    int oc = (idx >> 5) % Cout;
    int ck = idx / (32 * Cout);
    int k = ck * 32 + kk;
    int tap = k / Cin, ic = k % Cin;
    float v = (tap < K2) ? w[((size_t)oc * Cin + ic) * K2 + tap] : 0.0f;
    Wk[idx] = f2bfu(v);
}

// ================= fused front-end: patch_sum (640 blk) | q_gemm (256 blk) | prep (128 blk) ===
// 512 threads per block; roles selected by blockIdx.x range. Roles are independent; BW-bound
// patch blocks co-schedule with VALU-bound q_gemm blocks (pipe overlap = max, not sum).
__global__ __launch_bounds__(512) void fused_front(
        const float* __restrict__ x0, const float* __restrict__ x1,
        const float* __restrict__ x2, const float* __restrict__ x3,
        const float* __restrict__ dox,
        const float* __restrict__ wq, const float* __restrict__ bq,
        const float* __restrict__ wsm,
        const float* __restrict__ cw1, const float* __restrict__ cw2, const float* __restrict__ cw3,
        uint16_t* __restrict__ PS, float* __restrict__ inv, float* __restrict__ mexpb,
        uint16_t* __restrict__ Qbf,
        uint16_t* __restrict__ WB, uint16_t* __restrict__ Wk1,
        uint16_t* __restrict__ Wk2, uint16_t* __restrict__ Wk3) {
    int b = blockIdx.x;
    int tid = threadIdx.x;
    __shared__ float wls[4][64];
    __shared__ uint16_t pst[2][2][16][72];   // [hg][fb][q][ch]
    __shared__ uint32_t Al[16][68];

    if (b < 640) {
        // ---------- PATCH_SUM role: 2 chq-halves x 256 threads ----------
        int z = b >> 5, rem_b = b & 31;
        int p1 = rem_b & 15, chqh = rem_b >> 4;
        int hg = tid >> 8, t2 = tid & 255;
        int chq = chqh * 2 + hg;
        int sc = z / 5, k = z % 5;
        const float* xim = ((sc == 0) ? x0 : (sc == 1) ? x1 : (sc == 2) ? x2 : x3)
                           + (size_t)(k + 1) * CCH * NPIX;
        int cloc = t2 >> 6, col = t2 & 63;
        if (tid < 256)
            wls[cloc][col] = dox[(size_t)k * 65536 + (size_t)(16 * p1 + 4 * cloc) * 256 + 4 * col];
        __syncthreads();
        float w0 = wls[0][col], w1 = wls[1][col], w2 = wls[2][col], w3 = wls[3][col];
        const float* xbase = xim + p1 * 256 + col;
#pragma unroll 4
        for (int it = 0; it < 16; ++it) {
            int c = chq * 64 + it * 4 + cloc;
            const float* xp = xbase + (size_t)c * NPIX;
            float v0 = xp[0], v1 = xp[64], v2 = xp[128], v3 = xp[192];
            float pf = w0 * v0 + w1 * v1 + w2 * v2 + w3 * v3;
            float pb = (v0 + v1 + v2 + v3) - pf;
            pf += __shfl_xor(pf, 1); pf += __shfl_xor(pf, 2);
            pb += __shfl_xor(pb, 1); pb += __shfl_xor(pb, 2);
            if ((col & 3) == 0) {
                int q = col >> 2, cl = it * 4 + cloc;
                pst[hg][0][q][cl] = f2bfu(pf);
                pst[hg][1][q][cl] = f2bfu(pb);
            }
        }
        if (chq == 0 && t2 < 64 && tid < 64) {
            float ws = w0 + w1 + w2 + w3;
            ws += __shfl_xor(ws, 1); ws += __shfl_xor(ws, 2);
            if ((col & 3) == 0) {
                int s = p1 * 16 + (col >> 2);
                float fsum = ws, bsum = 16.f - ws;
                int mf = k * 512 + s, mbk = mf + 256;
                mexpb[sc * M2 + mf]  = (fsum < 1.f) ? 0.f : 1.f;
                mexpb[sc * M2 + mbk] = (bsum < 1.f) ? 0.f : 1.f;
                inv[(size_t)(z * 2 + 0) * 256 + s] = 1.f / fmaxf(fsum, 1e-6f);
                inv[(size_t)(z * 2 + 1) * 256 + s] = 1.f / fmaxf(bsum, 1e-6f);
            }
        }
        __syncthreads();
        int fb = t2 >> 7, rem = t2 & 127;
        int q = rem >> 3, chunk = rem & 7;
        uint4 v = *(const uint4*)&pst[hg][fb][q][chunk * 8];
        int s = p1 * 16 + q;
        *(uint4*)&PS[((size_t)(z * 2 + fb) * 256 + s) * CCH + chq * 64 + chunk * 8] = v;
    } else if (b < 896) {
        // ---------- Q_GEMM role (img 0 only; B-frags packed from f32 wq) ----------
        int bb = b - 640;
        int sc = bb >> 6;
        int p0 = (bb & 63) * 64;
        const float* xim = (sc == 0) ? x0 : (sc == 1) ? x1 : (sc == 2) ? x2 : x3;
        int lane = tid & 63, wid = tid >> 6;
        int lp = lane & 15, g = lane >> 4;
        int wm = wid >> 1, wn = wid & 1;
        f32x4 acc[8] = {};
#pragma unroll
        for (int ks = 0; ks < 8; ++ks) {
            int k0 = ks * 32;
            __syncthreads();
            if (tid < 256) {
                int rp = tid >> 4, f4i = tid & 15;
                float4 v0 = *(const float4*)(xim + (size_t)(k0 + 2 * rp) * NPIX + p0 + f4i * 4);
                float4 v1 = *(const float4*)(xim + (size_t)(k0 + 2 * rp + 1) * NPIX + p0 + f4i * 4);
                *(uint4*)&Al[rp][f4i * 4] = make_uint4(
                    pack_bf2(v0.x, v1.x), pack_bf2(v0.y, v1.y),
                    pack_bf2(v0.z, v1.z), pack_bf2(v0.w, v1.w));
            }
            __syncthreads();
            short8 bfr[8];
#pragma unroll
            for (int tn = 0; tn < 8; ++tn) {
                const float* wr = wq + (size_t)(wn * 128 + tn * 16 + lp) * 256 + k0 + g * 8;
                float4 f0 = *(const float4*)wr;
                float4 f1 = *(const float4*)(wr + 4);
                bfr[tn] = mk8(pack_bf2(f0.x, f0.y), pack_bf2(f0.z, f0.w),
                              pack_bf2(f1.x, f1.y), pack_bf2(f1.z, f1.w));
            }
            int px = wm * 16 + lp;
            uint4 av = make_uint4(Al[4 * g + 0][px], Al[4 * g + 1][px],
                                  Al[4 * g + 2][px], Al[4 * g + 3][px]);
            short8 af = u4_to_s8(av);
#pragma unroll
            for (int tn = 0; tn < 8; ++tn)
                acc[tn] = __builtin_amdgcn_mfma_f32_16x16x32_bf16(af, bfr[tn], acc[tn], 0, 0, 0);
        }
#pragma unroll
        for (int tn = 0; tn < 8; ++tn) {
            int co = wn * 128 + tn * 16 + lp;
            float bv = bq[co];
#pragma unroll
            for (int r = 0; r < 4; ++r) {
                int row = p0 + wm * 16 + g * 4 + r;
                Qbf[((size_t)(sc * NPIX + row)) * CCH + co] = f2bfu((acc[tn][r] + bv) * LOG2E);
            }
        }
    } else {
        // ---------- PREP role: WB (bf16 weights) + conv Wk1/Wk2/Wk3 ----------
        int idx0 = (b - 896) * 512 + tid;
        for (int i = idx0; i < 233472; i += 65536) {
            int idx = i;
            if (idx < 131072) {
                const float* src = (idx < 65536) ? wq : wsm;
                WB[idx] = f2bfu(src[idx & 65535]);
                continue;
            }
            idx -= 131072;
            if (idx < 2048)  { prep_w_one(cw1, Wk1, idx, 4, 16, 25);  continue; }
            idx -= 2048;
            if (idx < 26624) { prep_w_one(cw2, Wk2, idx, 16, 64, 25); continue; }
            idx -= 26624;
            if (idx < 73728) { prep_w_one(cw3, Wk3, idx, 64, 128, 9); continue; }
        }
    }
}

// ---------------- centroid GEMM: Cs = W.(psum)*inv + b ----------------
__global__ __launch_bounds__(256) void cent_gemm(
        const uint16_t* __restrict__ PS, const uint16_t* __restrict__ WB,
        const float* __restrict__ bs, const float* __restrict__ inv,
        uint16_t* __restrict__ Csbf) {
    int tid = threadIdx.x, lane = tid & 63, wid = tid >> 6;
    int lp = lane & 15, g = lane >> 4;
    int rowb = blockIdx.x * 128 + wid * 32;
    int cob = blockIdx.y * 64;
    const uint16_t* wsb = WB + 65536;
    f32x4 acc[2][4] = {};
#pragma unroll
    for (int ks = 0; ks < 8; ++ks) {
        int k0 = ks * 32;
        uint4 a0 = *(const uint4*)(PS + (size_t)(rowb + lp) * CCH + k0 + g * 8);
        uint4 a1 = *(const uint4*)(PS + (size_t)(rowb + 16 + lp) * CCH + k0 + g * 8);
        short8 af[2] = {u4_to_s8(a0), u4_to_s8(a1)};
        short8 b[4];
#pragma unroll
        for (int t = 0; t < 4; ++t) {
            uint4 bw = *(const uint4*)(wsb + (size_t)(cob + t * 16 + lp) * 256 + k0 + g * 8);
            b[t] = u4_to_s8(bw);
        }
#pragma unroll
        for (int m = 0; m < 2; ++m)
#pragma unroll
            for (int t = 0; t < 4; ++t)
                acc[m][t] = __builtin_amdgcn_mfma_f32_16x16x32_bf16(af[m], b[t], acc[m][t], 0, 0, 0);
    }
#pragma unroll
    for (int m = 0; m < 2; ++m)
#pragma unroll
        for (int t = 0; t < 4; ++t) {
            int co = cob + t * 16 + lp;
            int h = co >> 5, d = co & 31;
            float bv = bs[co];
#pragma unroll
            for (int r = 0; r < 4; ++r) {
                int row = rowb + m * 16 + g * 4 + r;
                int zz = row >> 9, fb = (row >> 8) & 1, s = row & 255;
                int scc = zz / 5, kk = zz % 5;
                int slot = kk * 512 + fb * 256 + s;
                float val = acc[m][t][r] * inv[row] + bv;
                Csbf[(((size_t)scc * NH + h) * M2 + slot) * 32 + d] = f2bfu(val);
            }
        }
}

// ---------------- attention v6: multiplicative mask, zero C-init, B-frags from L2 ----------
__global__ __launch_bounds__(256) void attn_v6(
        const uint16_t* __restrict__ Qbf, const uint16_t* __restrict__ Csbf,
        const float* __restrict__ mexpb, float* __restrict__ sfbuf) {
    int head = blockIdx.y;
    int sc = blockIdx.z >> 2, split = blockIdx.z & 3;
    int tid = threadIdx.x;
    int lane = tid & 63, wid = tid >> 6;
    int lp = lane & 15, g = lane >> 4;
    int p0w = blockIdx.x * 256 + wid * 64;

    const uint16_t* Qs = Qbf + (size_t)sc * NPIX * CCH;
    const uint16_t* csb = Csbf + ((size_t)sc * NH + head) * M2 * 32;
    const float* mb = mexpb + sc * M2;

    short8 aq[4];
#pragma unroll
    for (int m = 0; m < 4; m++) {
        uint4 qv = *(const uint4*)(Qs + (size_t)(p0w + m * 16 + lp) * CCH + head * 32 + g * 8);
        aq[m] = u4_to_s8(qv);
    }

    const f32x4 zero4 = {0.f, 0.f, 0.f, 0.f};
    float sfg[4][4] = {}, sbg[4][4] = {};
    int cbeg = split * 640;
    for (int c0loc = 0; c0loc < 640; c0loc += 64) {
        int c0 = cbeg + c0loc;
        bool fg = ((c0 & 511) < 256);
        short8 bf[4];
        float mexp[4];
#pragma unroll
        for (int t = 0; t < 4; t++) {
            int row = c0 + t * 16 + lp;
            bf[t] = u4_to_s8(*(const uint4*)(csb + (size_t)row * 32 + g * 8));
            mexp[t] = mb[row];
        }
        if (fg) {
#pragma unroll
            for (int m = 0; m < 4; m++)
#pragma unroll
                for (int t = 0; t < 4; t++) {
                    f32x4 c = __builtin_amdgcn_mfma_f32_16x16x32_bf16(aq[m], bf[t], zero4, 0, 0, 0);
#pragma unroll
                    for (int r = 0; r < 4; r++)
                        sfg[m][r] = fmaf(__builtin_amdgcn_exp2f(c[r]), mexp[t], sfg[m][r]);
                }
        } else {
#pragma unroll
            for (int m = 0; m < 4; m++)
#pragma unroll
                for (int t = 0; t < 4; t++) {
                    f32x4 c = __builtin_amdgcn_mfma_f32_16x16x32_bf16(aq[m], bf[t], zero4, 0, 0, 0);
#pragma unroll
                    for (int r = 0; r < 4; r++)
                        sbg[m][r] = fmaf(__builtin_amdgcn_exp2f(c[r]), mexp[t], sbg[m][r]);
                }
        }
    }
#pragma unroll
    for (int m = 0; m < 4; m++)
#pragma unroll
        for (int r = 0; r < 4; r++) {
#pragma unroll
            for (int msk = 1; msk < 16; msk <<= 1) {
                sfg[m][r] += __shfl_xor(sfg[m][r], msk);
                sbg[m][r] += __shfl_xor(sbg[m][r], msk);
            }
        }
    if (lp == 0) {
        float* sf = sfbuf + (size_t)((sc * 4 + split) * 2) * NH * NPIX;
        float* so = sf + (size_t)head * NPIX;
        float* fo = sf + (size_t)(NH + head) * NPIX;
#pragma unroll
        for (int m = 0; m < 4; m++)
#pragma unroll
            for (int r = 0; r < 4; r++) {
                int px = p0w + m * 16 + g * 4 + r;
                so[px] = sfg[m][r] + sbg[m][r];
                fo[px] = sfg[m][r];
            }
    }
}

// ---------------- head mean over 4 split partials ----------------
__global__ void mean_heads3(const float* __restrict__ sfbuf, float* __restrict__ cm) {
    int idx = blockIdx.x * 256 + threadIdx.x;
    int sc = idx >> 12, p = idx & 4095;
    const float* b = sfbuf + (size_t)sc * 4 * 2 * NH * NPIX;
    float acc = 0.f;
#pragma unroll
    for (int h = 0; h < NH; h++) {
        float sv = 0.f, fv = 0.f;
#pragma unroll
        for (int sp = 0; sp < 4; sp++) {
            sv += b[((size_t)(sp * 2) * NH + h) * NPIX + p];
            fv += b[((size_t)(sp * 2 + 1) * NH + h) * NPIX + p];
        }
        acc += fv / sv;
    }
    cm[idx] = 0.125f * acc;
}

// ---------------- implicit-GEMM conv + fused GN(on-load) + GN-partials (epilogue) --------
template<int CIN, int COUT, int KSZ, int NPIN, int NPOUT, bool GNIN>
__global__ __launch_bounds__(256) void conv_mfma(
        const float* __restrict__ in, const uint16_t* __restrict__ Wk,
        const float* __restrict__ bias,
        const float* __restrict__ gin, const float* __restrict__ bein,
        const float2* __restrict__ pin,
        float* __restrict__ out, float2* __restrict__ pout) {
    constexpr int PAD = KSZ / 2;
    constexpr int NTAP = KSZ * KSZ;
    constexpr int K = CIN * NTAP;
    constexpr int CK = (K + 31) / 32;
    constexpr int PXP = 64 + 2 * PAD;
    constexpr int ICB = (CIN >= 8) ? CIN / 8 : 1;
    __shared__ uint16_t Xs[KSZ * PXP * CIN];
    __shared__ float gaL[CIN], beL[CIN];
    __shared__ float gmu[4], grs[4];
    int tid = threadIdx.x;
    int lane = tid & 63, wv = tid >> 6;
    int lp = lane & 15, g = lane >> 4;
    int y = blockIdx.x;
    int oc0 = blockIdx.y * 64;

    if (GNIN) {
        float s = 0.f, s2 = 0.f;
        for (int i = lane; i < NPIN; i += 64) {
            float2 p = pin[wv * NPIN + i];
            s += p.x; s2 += p.y;
        }
#pragma unroll
        for (int m = 32; m; m >>= 1) { s += __shfl_xor(s, m); s2 += __shfl_xor(s2, m); }
        if (lane == 0) {
            float n = (float)((CIN / 4) * NPIX);
            float mu = s / n;
            gmu[wv] = mu;
            grs[wv] = rsqrtf(s2 / n - mu * mu + 1e-5f);
        }
        __syncthreads();
        if (tid < CIN) {
            int gg = tid / (CIN / 4);
            float ga = gin[tid] * grs[gg];
            gaL[tid] = ga;
            beL[tid] = bein[tid] - gmu[gg] * ga;
        }
        __syncthreads();
    }

    if (CIN >= 8) {
        for (int idx = tid; idx < KSZ * ICB * PXP; idx += 256) {
            int pxp = idx % PXP; int rem = idx / PXP;
            int icb = rem % ICB; int r = rem / ICB;
            int gy = y + r - PAD, gx = pxp - PAD;
            bool ok = ((unsigned)gy < 64u) && ((unsigned)gx < 64u);
            const float* ip = in + (size_t)(icb * 8) * NPIX + gy * 64 + gx;
            uint32_t wb[4];
#pragma unroll
            for (int j = 0; j < 4; j++) {
                int c0c = icb * 8 + 2 * j, c1c = c0c + 1;
                float v0 = ok ? ip[(size_t)(2 * j) * NPIX] : 0.f;
                float v1 = ok ? ip[(size_t)(2 * j + 1) * NPIX] : 0.f;
                if (GNIN) {
                    v0 = fmaf(v0, gaL[c0c], beL[c0c]); v0 = v0 > 0.f ? v0 : 0.f;
                    v1 = fmaf(v1, gaL[c1c], beL[c1c]); v1 = v1 > 0.f ? v1 : 0.f;
                    if (!ok) { v0 = 0.f; v1 = 0.f; }
                }
                wb[j] = pack_bf2(v0, v1);
            }
            *(uint4*)&Xs[(size_t)idx * 8] = make_uint4(wb[0], wb[1], wb[2], wb[3]);
        }
    } else {
        for (int idx = tid; idx < KSZ * PXP; idx += 256) {
            int pxp = idx % PXP; int r = idx / PXP;
            int gy = y + r - PAD, gx = pxp - PAD;
            bool ok = ((unsigned)gy < 64u) && ((unsigned)gx < 64u);
            const float* ip = in + (size_t)gy * 64 + gx;
            float v0 = ok ? ip[0] : 0.f, v1 = ok ? ip[NPIX] : 0.f;
            float v2 = ok ? ip[2 * NPIX] : 0.f, v3 = ok ? ip[3 * NPIX] : 0.f;
            *(uint2*)&Xs[(size_t)idx * 4] = make_uint2(pack_bf2(v0, v1), pack_bf2(v2, v3));
        }
    }
    __syncthreads();

    int tmb, tme, tn;
    if (COUT >= 64) { tn = wv; tmb = 0; tme = 4; }
    else            { tn = 0;  tmb = wv; tme = wv + 1; }
    int oc = oc0 + tn * 16 + lp;
    f32x4 acc[4] = {};

#pragma unroll
    for (int ck = 0; ck < CK; ck++) {
        const uint16_t* wp = Wk + ((size_t)ck * COUT + oc) * 32 + g * 8;
        uint4 bw = *(const uint4*)wp;
        short8 bfr = u4_to_s8(bw);
        if (CIN >= 8) {
            int gk = ck * 4 + g;
            int tap = gk / ICB; if (tap > NTAP - 1) tap = NTAP - 1;
            int icb = gk % ICB;
            int r = tap / KSZ, dx = tap % KSZ;
            int base = (r * ICB + icb) * PXP * 8;
            for (int tm = tmb; tm < tme; tm++) {
                int pxp = tm * 16 + lp + dx;
                uint4 av = *(const uint4*)&Xs[base + pxp * 8];
                short8 afr = u4_to_s8(av);
                acc[tm] = __builtin_amdgcn_mfma_f32_16x16x32_bf16(afr, bfr, acc[tm], 0, 0, 0);
            }
        } else {
            int gk = ck * 4 + g;
            int t0 = 2 * gk;     if (t0 > NTAP - 1) t0 = NTAP - 1;
            int t1 = 2 * gk + 1; if (t1 > NTAP - 1) t1 = NTAP - 1;
            int r0 = t0 / KSZ, dx0 = t0 % KSZ;
            int r1 = t1 / KSZ, dx1 = t1 % KSZ;
            for (int tm = tmb; tm < tme; tm++) {
                uint2 a0 = *(const uint2*)&Xs[((size_t)(r0 * PXP + tm * 16 + lp + dx0)) * 4];
                uint2 a1 = *(const uint2*)&Xs[((size_t)(r1 * PXP + tm * 16 + lp + dx1)) * 4];
                uint4 av = make_uint4(a0.x, a0.y, a1.x, a1.y);
                short8 afr = u4_to_s8(av);
                acc[tm] = __builtin_amdgcn_mfma_f32_16x16x32_bf16(afr, bfr, acc[tm], 0, 0, 0);
            }
        }
    }
    float bv = bias[oc];
    float ps = 0.f, ps2 = 0.f;
    for (int tm = tmb; tm < tme; tm++)
#pragma unroll
        for (int r = 0; r < 4; r++) {
            int px = tm * 16 + g * 4 + r;
            float val = acc[tm][r] + bv;
            out[(size_t)oc * NPIX + y * 64 + px] = val;
            ps += val;
            ps2 = fmaf(val, val, ps2);
        }
    if (COUT >= 64) {
#pragma unroll
        for (int m = 32; m; m >>= 1) { ps += __shfl_xor(ps, m); ps2 += __shfl_xor(ps2, m); }
        if (lane == 0) {
            if (COUT == 64) {
                pout[wv * NPOUT + y] = make_float2(ps, ps2);
            } else {
                int grp = blockIdx.y * 2 + (wv >> 1);
                pout[grp * NPOUT + y * 2 + (wv & 1)] = make_float2(ps, ps2);
            }
        }
    } else {
#pragma unroll
        for (int m : {1, 2, 16, 32}) { ps += __shfl_xor(ps, m); ps2 += __shfl_xor(ps2, m); }
        int q = (lane >> 2) & 3;
        if (lane == q * 4)
            pout[q * NPOUT + y * 4 + wv] = make_float2(ps, ps2);
    }
}

// ---------------- final GN apply + relu (reads float2 partials) ----------------
__global__ __launch_bounds__(256) void gn_apply_relu(const float* __restrict__ in, const float2* __restrict__ part,
                                                     const float* __restrict__ gamma, const float* __restrict__ beta,
                                                     int Cg, int npart, float* __restrict__ out) {
    int idx4 = blockIdx.x * 256 + threadIdx.x;
    int c = idx4 >> 10;
    int g = c / Cg;
    float s = 0.0f, s2 = 0.0f;
    for (int b = 0; b < npart; b++) {
        float2 p = part[g * npart + b];
        s += p.x; s2 += p.y;
    }
    float n = (float)(Cg * NPIX);
    float mu = s / n;
    float rstd = rsqrtf(s2 / n - mu * mu + 1e-5f);
    float ga = gamma[c] * rstd;
    float be = beta[c] - mu * ga;
    float4 v = ((const float4*)in)[idx4];
    float4 o;
    o.x = fmaf(v.x, ga, be); o.x = o.x > 0.f ? o.x : 0.f;
    o.y = fmaf(v.y, ga, be); o.y = o.y > 0.f ? o.y : 0.f;
    o.z = fmaf(v.z, ga, be); o.z = o.z > 0.f ? o.z : 0.f;
    o.w = fmaf(v.w, ga, be); o.w = o.w > 0.f ? o.w : 0.f;
    ((float4*)out)[idx4] = o;
}

// ---------------- launch ----------------
extern "C" void kernel_launch(void* const* d_in, const int* in_sizes, int n_in,
                              void* d_out, int out_size, void* d_ws, size_t ws_size,
                              hipStream_t stream) {
    const float* x0 = (const float*)d_in[0];
    const float* x1 = (const float*)d_in[1];
    const float* x2 = (const float*)d_in[2];
    const float* x3 = (const float*)d_in[3];
    const float* dox = (const float*)d_in[4];
    const float* wq  = (const float*)d_in[5];
    const float* bq  = (const float*)d_in[6];
    const float* wsm = (const float*)d_in[7];
    const float* bs  = (const float*)d_in[8];
    const float* cw1 = (const float*)d_in[9];
    const float* cb1 = (const float*)d_in[10];
    const float* g1  = (const float*)d_in[11];
    const float* be1 = (const float*)d_in[12];
    const float* cw2 = (const float*)d_in[13];
    const float* cb2 = (const float*)d_in[14];
    const float* g2  = (const float*)d_in[15];
    const float* be2 = (const float*)d_in[16];
    const float* cw3 = (const float*)d_in[17];
    const float* cb3 = (const float*)d_in[18];
    const float* g3  = (const float*)d_in[19];
    const float* be3 = (const float*)d_in[20];

    // u16 region
    uint16_t* Qbf  = (uint16_t*)d_ws;                        // 4194304
    uint16_t* Csbf = Qbf + (size_t)4194304;                  // 2621440
    uint16_t* PS   = Csbf + (size_t)2621440;                 // 2621440
    uint16_t* WB   = PS + (size_t)2621440;                   // 131072
    uint16_t* Wk1  = WB + 131072;                            // 2048
    uint16_t* Wk2  = Wk1 + 2048;                             // 26624
    uint16_t* Wk3  = Wk2 + 26624;                            // 73728
    // float region
    float* fbase  = (float*)(Wk3 + 73728);
    float* mexpb  = fbase;                 // 10240
    float* inv    = mexpb + 10240;         // 10240
    float* sfbuf  = inv + 10240;           // 1048576
    float* cm     = sfbuf + 1048576;       // 16384
    float* h1     = cm + 16384;            // 65536
    float* h2     = h1 + 65536;            // 262144
    float* h3     = h2 + 262144;           // 524288
    float2* part1 = (float2*)(h3 + 524288);   // 4*256 f2
    float2* part2 = part1 + 4 * 256;          // 4*64 f2
    float2* part3 = part2 + 4 * 64;           // 4*128 f2

    // fused front-end: patch_sum | q_gemm | prep  (roles co-resident)
    fused_front<<<1024, 512, 0, stream>>>(x0, x1, x2, x3, dox, wq, bq, wsm,
                                          cw1, cw2, cw3,
                                          PS, inv, mexpb, Qbf, WB, Wk1, Wk2, Wk3);

    cent_gemm<<<dim3(80, 4), 256, 0, stream>>>(PS, WB, bs, inv, Csbf);
    attn_v6<<<dim3(16, NH, 16), 256, 0, stream>>>(Qbf, Csbf, mexpb, sfbuf);
    mean_heads3<<<64, 256, 0, stream>>>(sfbuf, cm);

    conv_mfma<4, 16, 5, 1, 256, false><<<dim3(64, 1), 256, 0, stream>>>(
        cm, Wk1, cb1, nullptr, nullptr, nullptr, h1, part1);
    conv_mfma<16, 64, 5, 256, 64, true><<<dim3(64, 1), 256, 0, stream>>>(
        h1, Wk2, cb2, g1, be1, part1, h2, part2);
    conv_mfma<64, 128, 3, 64, 128, true><<<dim3(64, 2), 256, 0, stream>>>(
        h2, Wk3, cb3, g2, be2, part2, h3, part3);
    gn_apply_relu<<<(128 * 1024) / 256, 256, 0, stream>>>(h3, part3, g3, be3, 32, 128, (float*)d_out);
}

// Round 17
// 149.618 us; speedup vs baseline: 1.0938x; 1.0938x over previous
//
#include <hip/hip_runtime.h>
#include <hip/hip_bf16.h>
#include <stdint.h>

#define CCH 256
#define NPIX 4096      // 64*64
#define NH 8
#define M2 2560        // K*2*S
#define LOG2E 1.44269504088896f

typedef __attribute__((ext_vector_type(8))) short short8;
typedef __attribute__((ext_vector_type(4))) float f32x4;

__device__ __forceinline__ uint16_t f2bfu(float f) {
    uint32_t u = __builtin_bit_cast(uint32_t, f);
    return (uint16_t)((u + 0x7FFFu + ((u >> 16) & 1u)) >> 16);   // RNE
}
__device__ __forceinline__ uint32_t pack_bf2(float a, float b) {
    return (uint32_t)f2bfu(a) | ((uint32_t)f2bfu(b) << 16);
}
__device__ __forceinline__ short8 u4_to_s8(uint4 v) {
    return __builtin_bit_cast(short8, v);
}

// ---------------- fused prepack: WB (feature weights) + conv Wk1/Wk2/Wk3 ----------------
__device__ __forceinline__ void prep_w_one(const float* __restrict__ w, uint16_t* __restrict__ Wk,
                                           int idx, int Cin, int Cout, int K2) {
    int kk = idx & 31;
    int oc = (idx >> 5) % Cout;
    int ck = idx / (32 * Cout);
    int k = ck * 32 + kk;
    int tap = k / Cin, ic = k % Cin;
    float v = (tap < K2) ? w[((size_t)oc * Cin + ic) * K2 + tap] : 0.0f;
    Wk[idx] = f2bfu(v);
}

__global__ void prep_all(const float* __restrict__ wq, const float* __restrict__ wsm,
                         const float* __restrict__ cw1, const float* __restrict__ cw2,
                         const float* __restrict__ cw3,
                         uint16_t* __restrict__ WB, uint16_t* __restrict__ Wk1,
                         uint16_t* __restrict__ Wk2, uint16_t* __restrict__ Wk3) {
    int idx = blockIdx.x * 256 + threadIdx.x;
    if (idx < 131072) {
        const float* src = (idx < 65536) ? wq : wsm;
        WB[idx] = f2bfu(src[idx & 65535]);
        return;
    }
    idx -= 131072;
    if (idx < 2048)  { prep_w_one(cw1, Wk1, idx, 4, 16, 25);  return; }
    idx -= 2048;
    if (idx < 26624) { prep_w_one(cw2, Wk2, idx, 16, 64, 25); return; }
    idx -= 26624;
    if (idx < 73728) { prep_w_one(cw3, Wk3, idx, 64, 128, 9); return; }
}

// ---------------- patch-weighted sums of x (linearity: centroids = W.psum/fgs + b) ----------
__global__ __launch_bounds__(256) void patch_sum(
        const float* __restrict__ x0, const float* __restrict__ x1,
        const float* __restrict__ x2, const float* __restrict__ x3,
        const float* __restrict__ dox, uint16_t* __restrict__ PS,
        float* __restrict__ inv, float* __restrict__ mexpb) {
    int z = blockIdx.z;
    int sc = z / 5, k = z % 5;
    const float* xim = ((sc == 0) ? x0 : (sc == 1) ? x1 : (sc == 2) ? x2 : x3)
                       + (size_t)(k + 1) * CCH * NPIX;
    int p1 = blockIdx.x, chq = blockIdx.y;
    int tid = threadIdx.x;
    int cloc = tid >> 6, col = tid & 63;
    __shared__ float wls[4][64];
    __shared__ uint16_t pst[2][16][72];
    wls[cloc][col] = dox[(size_t)k * 65536 + (size_t)(16 * p1 + 4 * cloc) * 256 + 4 * col];
    __syncthreads();
    float w0 = wls[0][col], w1 = wls[1][col], w2 = wls[2][col], w3 = wls[3][col];
    const float* xbase = xim + p1 * 256 + col;
#pragma unroll 4
    for (int it = 0; it < 16; ++it) {
        int c = chq * 64 + it * 4 + cloc;
        const float* xp = xbase + (size_t)c * NPIX;
        float v0 = xp[0], v1 = xp[64], v2 = xp[128], v3 = xp[192];
        float pf = w0 * v0 + w1 * v1 + w2 * v2 + w3 * v3;
        float pb = (v0 + v1 + v2 + v3) - pf;
        pf += __shfl_xor(pf, 1); pf += __shfl_xor(pf, 2);
        pb += __shfl_xor(pb, 1); pb += __shfl_xor(pb, 2);
        if ((col & 3) == 0) {
            int q = col >> 2, cl = it * 4 + cloc;
            pst[0][q][cl] = f2bfu(pf);
            pst[1][q][cl] = f2bfu(pb);
        }
    }
    if (chq == 0 && tid < 64) {
        float ws = w0 + w1 + w2 + w3;
        ws += __shfl_xor(ws, 1); ws += __shfl_xor(ws, 2);
        if ((col & 3) == 0) {
            int s = p1 * 16 + (col >> 2);
            float fsum = ws, bsum = 16.f - ws;
            int mf = k * 512 + s, mbk = mf + 256;
            mexpb[sc * M2 + mf]  = (fsum < 1.f) ? 0.f : 1.f;
            mexpb[sc * M2 + mbk] = (bsum < 1.f) ? 0.f : 1.f;
            inv[(size_t)(z * 2 + 0) * 256 + s] = 1.f / fmaxf(fsum, 1e-6f);
            inv[(size_t)(z * 2 + 1) * 256 + s] = 1.f / fmaxf(bsum, 1e-6f);
        }
    }
    __syncthreads();
    int fb = tid >> 7, rem = tid & 127;
    int q = rem >> 3, chunk = rem & 7;
    uint4 v = *(const uint4*)&pst[fb][q][chunk * 8];
    int s = p1 * 16 + q;
    *(uint4*)&PS[((size_t)(z * 2 + fb) * 256 + s) * CCH + chq * 64 + chunk * 8] = v;
}

// ---------------- centroid GEMM: Cs = W.(psum)*inv + b ----------------
__global__ __launch_bounds__(256) void cent_gemm(
        const uint16_t* __restrict__ PS, const uint16_t* __restrict__ WB,
        const float* __restrict__ bs, const float* __restrict__ inv,
        uint16_t* __restrict__ Csbf) {
    int tid = threadIdx.x, lane = tid & 63, wid = tid >> 6;
    int lp = lane & 15, g = lane >> 4;
    int rowb = blockIdx.x * 128 + wid * 32;
    int cob = blockIdx.y * 64;
    const uint16_t* wsb = WB + 65536;
    f32x4 acc[2][4] = {};
#pragma unroll
    for (int ks = 0; ks < 8; ++ks) {
        int k0 = ks * 32;
        uint4 a0 = *(const uint4*)(PS + (size_t)(rowb + lp) * CCH + k0 + g * 8);
        uint4 a1 = *(const uint4*)(PS + (size_t)(rowb + 16 + lp) * CCH + k0 + g * 8);
        short8 af[2] = {u4_to_s8(a0), u4_to_s8(a1)};
        short8 b[4];
#pragma unroll
        for (int t = 0; t < 4; ++t) {
            uint4 bw = *(const uint4*)(wsb + (size_t)(cob + t * 16 + lp) * 256 + k0 + g * 8);
            b[t] = u4_to_s8(bw);
        }
#pragma unroll
        for (int m = 0; m < 2; ++m)
#pragma unroll
            for (int t = 0; t < 4; ++t)
                acc[m][t] = __builtin_amdgcn_mfma_f32_16x16x32_bf16(af[m], b[t], acc[m][t], 0, 0, 0);
    }
#pragma unroll
    for (int m = 0; m < 2; ++m)
#pragma unroll
        for (int t = 0; t < 4; ++t) {
            int co = cob + t * 16 + lp;
            int h = co >> 5, d = co & 31;
            float bv = bs[co];
#pragma unroll
            for (int r = 0; r < 4; ++r) {
                int row = rowb + m * 16 + g * 4 + r;
                int zz = row >> 9, fb = (row >> 8) & 1, s = row & 255;
                int scc = zz / 5, kk = zz % 5;
                int slot = kk * 512 + fb * 256 + s;
                float val = acc[m][t][r] * inv[row] + bv;
                Csbf[(((size_t)scc * NH + h) * M2 + slot) * 32 + d] = f2bfu(val);
            }
        }
}

// ---------------- Q GEMM (img 0 only) ----------------
__global__ __launch_bounds__(512) void q_gemm(
        const float* __restrict__ x0, const float* __restrict__ x1,
        const float* __restrict__ x2, const float* __restrict__ x3,
        const uint16_t* __restrict__ WB, const float* __restrict__ bq,
        uint16_t* __restrict__ Qbf) {
    int sc = blockIdx.y;
    const float* xim = (sc == 0) ? x0 : (sc == 1) ? x1 : (sc == 2) ? x2 : x3;
    int p0 = blockIdx.x * 64;
    int tid = threadIdx.x, lane = tid & 63, wid = tid >> 6;
    int lp = lane & 15, g = lane >> 4;
    int wm = wid >> 1, wn = wid & 1;
    __shared__ uint32_t Al[16][68];
    f32x4 acc[8] = {};
#pragma unroll
    for (int ks = 0; ks < 8; ++ks) {
        int k0 = ks * 32;
        __syncthreads();
        if (tid < 256) {
            int rp = tid >> 4, f4i = tid & 15;
            float4 v0 = *(const float4*)(xim + (size_t)(k0 + 2 * rp) * NPIX + p0 + f4i * 4);
            float4 v1 = *(const float4*)(xim + (size_t)(k0 + 2 * rp + 1) * NPIX + p0 + f4i * 4);
            *(uint4*)&Al[rp][f4i * 4] = make_uint4(
                pack_bf2(v0.x, v1.x), pack_bf2(v0.y, v1.y),
                pack_bf2(v0.z, v1.z), pack_bf2(v0.w, v1.w));
        }
        __syncthreads();
        short8 b[8];
#pragma unroll
        for (int tn = 0; tn < 8; ++tn) {
            uint4 bw = *(const uint4*)(WB + (size_t)(wn * 128 + tn * 16 + lp) * 256 + k0 + g * 8);
            b[tn] = u4_to_s8(bw);
        }
        int px = wm * 16 + lp;
        uint4 av = make_uint4(Al[4 * g + 0][px], Al[4 * g + 1][px],
                              Al[4 * g + 2][px], Al[4 * g + 3][px]);
        short8 af = u4_to_s8(av);
#pragma unroll
        for (int tn = 0; tn < 8; ++tn)
            acc[tn] = __builtin_amdgcn_mfma_f32_16x16x32_bf16(af, b[tn], acc[tn], 0, 0, 0);
    }
#pragma unroll
    for (int tn = 0; tn < 8; ++tn) {
        int co = wn * 128 + tn * 16 + lp;
        float bv = bq[co];
#pragma unroll
        for (int r = 0; r < 4; ++r) {
            int row = p0 + wm * 16 + g * 4 + r;
            Qbf[((size_t)(sc * NPIX + row)) * CCH + co] = f2bfu((acc[tn][r] + bv) * LOG2E);
        }
    }
}

// ---------------- attention v8: v6 with 8 slot-splits (320 slots/block, 4096 blocks) --------
__global__ __launch_bounds__(256) void attn_v8(
        const uint16_t* __restrict__ Qbf, const uint16_t* __restrict__ Csbf,
        const float* __restrict__ mexpb, float* __restrict__ sfbuf) {
    int head = blockIdx.y;
    int sc = blockIdx.z >> 3, split = blockIdx.z & 7;
    int tid = threadIdx.x;
    int lane = tid & 63, wid = tid >> 6;
    int lp = lane & 15, g = lane >> 4;
    int p0w = blockIdx.x * 256 + wid * 64;

    const uint16_t* Qs = Qbf + (size_t)sc * NPIX * CCH;
    const uint16_t* csb = Csbf + ((size_t)sc * NH + head) * M2 * 32;
    const float* mb = mexpb + sc * M2;

    short8 aq[4];
#pragma unroll
    for (int m = 0; m < 4; m++) {
        uint4 qv = *(const uint4*)(Qs + (size_t)(p0w + m * 16 + lp) * CCH + head * 32 + g * 8);
        aq[m] = u4_to_s8(qv);
    }

    const f32x4 zero4 = {0.f, 0.f, 0.f, 0.f};
    float sfg[4][4] = {}, sbg[4][4] = {};
    int cbeg = split * 320;
    for (int c0loc = 0; c0loc < 320; c0loc += 64) {
        int c0 = cbeg + c0loc;
        bool fg = ((c0 & 511) < 256);
        short8 bf[4];
        float mexp[4];
#pragma unroll
        for (int t = 0; t < 4; t++) {
            int row = c0 + t * 16 + lp;
            bf[t] = u4_to_s8(*(const uint4*)(csb + (size_t)row * 32 + g * 8));
            mexp[t] = mb[row];
        }
        if (fg) {
#pragma unroll
            for (int m = 0; m < 4; m++)
#pragma unroll
                for (int t = 0; t < 4; t++) {
                    f32x4 c = __builtin_amdgcn_mfma_f32_16x16x32_bf16(aq[m], bf[t], zero4, 0, 0, 0);
#pragma unroll
                    for (int r = 0; r < 4; r++)
                        sfg[m][r] = fmaf(__builtin_amdgcn_exp2f(c[r]), mexp[t], sfg[m][r]);
                }
        } else {
#pragma unroll
            for (int m = 0; m < 4; m++)
#pragma unroll
                for (int t = 0; t < 4; t++) {
                    f32x4 c = __builtin_amdgcn_mfma_f32_16x16x32_bf16(aq[m], bf[t], zero4, 0, 0, 0);
#pragma unroll
                    for (int r = 0; r < 4; r++)
                        sbg[m][r] = fmaf(__builtin_amdgcn_exp2f(c[r]), mexp[t], sbg[m][r]);
                }
        }
    }
#pragma unroll
    for (int m = 0; m < 4; m++)
#pragma unroll
        for (int r = 0; r < 4; r++) {
#pragma unroll
            for (int msk = 1; msk < 16; msk <<= 1) {
                sfg[m][r] += __shfl_xor(sfg[m][r], msk);
                sbg[m][r] += __shfl_xor(sbg[m][r], msk);
            }
        }
    if (lp == 0) {
        float* sf = sfbuf + (size_t)((sc * 8 + split) * 2) * NH * NPIX;
        float* so = sf + (size_t)head * NPIX;
        float* fo = sf + (size_t)(NH + head) * NPIX;
#pragma unroll
        for (int m = 0; m < 4; m++)
#pragma unroll
            for (int r = 0; r < 4; r++) {
                int px = p0w + m * 16 + g * 4 + r;
                so[px] = sfg[m][r] + sbg[m][r];
                fo[px] = sfg[m][r];
            }
    }
}

// ---------------- head mean over 8 split partials ----------------
__global__ void mean_heads4(const float* __restrict__ sfbuf, float* __restrict__ cm) {
    int idx = blockIdx.x * 256 + threadIdx.x;
    int sc = idx >> 12, p = idx & 4095;
    const float* b = sfbuf + (size_t)sc * 8 * 2 * NH * NPIX;
    float acc = 0.f;
#pragma unroll
    for (int h = 0; h < NH; h++) {
        float sv = 0.f, fv = 0.f;
#pragma unroll
        for (int sp = 0; sp < 8; sp++) {
            sv += b[((size_t)(sp * 2) * NH + h) * NPIX + p];
            fv += b[((size_t)(sp * 2 + 1) * NH + h) * NPIX + p];
        }
        acc += fv / sv;
    }
    cm[idx] = 0.125f * acc;
}

// ---------------- implicit-GEMM conv + fused GN(on-load) + GN-partials (epilogue) --------
template<int CIN, int COUT, int KSZ, int NPIN, int NPOUT, bool GNIN>
__global__ __launch_bounds__(256) void conv_mfma(
        const float* __restrict__ in, const uint16_t* __restrict__ Wk,
        const float* __restrict__ bias,
        const float* __restrict__ gin, const float* __restrict__ bein,
        const float2* __restrict__ pin,
        float* __restrict__ out, float2* __restrict__ pout) {
    constexpr int PAD = KSZ / 2;
    constexpr int NTAP = KSZ * KSZ;
    constexpr int K = CIN * NTAP;
    constexpr int CK = (K + 31) / 32;
    constexpr int PXP = 64 + 2 * PAD;
    constexpr int ICB = (CIN >= 8) ? CIN / 8 : 1;
    __shared__ uint16_t Xs[KSZ * PXP * CIN];
    __shared__ float gaL[CIN], beL[CIN];
    __shared__ float gmu[4], grs[4];
    int tid = threadIdx.x;
    int lane = tid & 63, wv = tid >> 6;
    int lp = lane & 15, g = lane >> 4;
    int y = blockIdx.x;
    int oc0 = blockIdx.y * 64;

    if (GNIN) {
        float s = 0.f, s2 = 0.f;
        for (int i = lane; i < NPIN; i += 64) {
            float2 p = pin[wv * NPIN + i];
            s += p.x; s2 += p.y;
        }
#pragma unroll
        for (int m = 32; m; m >>= 1) { s += __shfl_xor(s, m); s2 += __shfl_xor(s2, m); }
        if (lane == 0) {
            float n = (float)((CIN / 4) * NPIX);
            float mu = s / n;
            gmu[wv] = mu;
            grs[wv] = rsqrtf(s2 / n - mu * mu + 1e-5f);
        }
        __syncthreads();
        if (tid < CIN) {
            int gg = tid / (CIN / 4);
            float ga = gin[tid] * grs[gg];
            gaL[tid] = ga;
            beL[tid] = bein[tid] - gmu[gg] * ga;
        }
        __syncthreads();
    }

    if (CIN >= 8) {
        for (int idx = tid; idx < KSZ * ICB * PXP; idx += 256) {
            int pxp = idx % PXP; int rem = idx / PXP;
            int icb = rem % ICB; int r = rem / ICB;
            int gy = y + r - PAD, gx = pxp - PAD;
            bool ok = ((unsigned)gy < 64u) && ((unsigned)gx < 64u);
            const float* ip = in + (size_t)(icb * 8) * NPIX + gy * 64 + gx;
            uint32_t wb[4];
#pragma unroll
            for (int j = 0; j < 4; j++) {
                int c0c = icb * 8 + 2 * j, c1c = c0c + 1;
                float v0 = ok ? ip[(size_t)(2 * j) * NPIX] : 0.f;
                float v1 = ok ? ip[(size_t)(2 * j + 1) * NPIX] : 0.f;
                if (GNIN) {
                    v0 = fmaf(v0, gaL[c0c], beL[c0c]); v0 = v0 > 0.f ? v0 : 0.f;
                    v1 = fmaf(v1, gaL[c1c], beL[c1c]); v1 = v1 > 0.f ? v1 : 0.f;
                    if (!ok) { v0 = 0.f; v1 = 0.f; }
                }
                wb[j] = pack_bf2(v0, v1);
            }
            *(uint4*)&Xs[(size_t)idx * 8] = make_uint4(wb[0], wb[1], wb[2], wb[3]);
        }
    } else {
        for (int idx = tid; idx < KSZ * PXP; idx += 256) {
            int pxp = idx % PXP; int r = idx / PXP;
            int gy = y + r - PAD, gx = pxp - PAD;
            bool ok = ((unsigned)gy < 64u) && ((unsigned)gx < 64u);
            const float* ip = in + (size_t)gy * 64 + gx;
            float v0 = ok ? ip[0] : 0.f, v1 = ok ? ip[NPIX] : 0.f;
            float v2 = ok ? ip[2 * NPIX] : 0.f, v3 = ok ? ip[3 * NPIX] : 0.f;
            *(uint2*)&Xs[(size_t)idx * 4] = make_uint2(pack_bf2(v0, v1), pack_bf2(v2, v3));
        }
    }
    __syncthreads();

    int tmb, tme, tn;
    if (COUT >= 64) { tn = wv; tmb = 0; tme = 4; }
    else            { tn = 0;  tmb = wv; tme = wv + 1; }
    int oc = oc0 + tn * 16 + lp;
    f32x4 acc[4] = {};

#pragma unroll
    for (int ck = 0; ck < CK; ck++) {
        const uint16_t* wp = Wk + ((size_t)ck * COUT + oc) * 32 + g * 8;
        uint4 bw = *(const uint4*)wp;
        short8 bfr = u4_to_s8(bw);
        if (CIN >= 8) {
            int gk = ck * 4 + g;
            int tap = gk / ICB; if (tap > NTAP - 1) tap = NTAP - 1;
            int icb = gk % ICB;
            int r = tap / KSZ, dx = tap % KSZ;
            int base = (r * ICB + icb) * PXP * 8;
            for (int tm = tmb; tm < tme; tm++) {
                int pxp = tm * 16 + lp + dx;
                uint4 av = *(const uint4*)&Xs[base + pxp * 8];
                short8 afr = u4_to_s8(av);
                acc[tm] = __builtin_amdgcn_mfma_f32_16x16x32_bf16(afr, bfr, acc[tm], 0, 0, 0);
            }
        } else {
            int gk = ck * 4 + g;
            int t0 = 2 * gk;     if (t0 > NTAP - 1) t0 = NTAP - 1;
            int t1 = 2 * gk + 1; if (t1 > NTAP - 1) t1 = NTAP - 1;
            int r0 = t0 / KSZ, dx0 = t0 % KSZ;
            int r1 = t1 / KSZ, dx1 = t1 % KSZ;
            for (int tm = tmb; tm < tme; tm++) {
                uint2 a0 = *(const uint2*)&Xs[((size_t)(r0 * PXP + tm * 16 + lp + dx0)) * 4];
                uint2 a1 = *(const uint2*)&Xs[((size_t)(r1 * PXP + tm * 16 + lp + dx1)) * 4];
                uint4 av = make_uint4(a0.x, a0.y, a1.x, a1.y);
                short8 afr = u4_to_s8(av);
                acc[tm] = __builtin_amdgcn_mfma_f32_16x16x32_bf16(afr, bfr, acc[tm], 0, 0, 0);
            }
        }
    }
    float bv = bias[oc];
    float ps = 0.f, ps2 = 0.f;
    for (int tm = tmb; tm < tme; tm++)
#pragma unroll
        for (int r = 0; r < 4; r++) {
            int px = tm * 16 + g * 4 + r;
            float val = acc[tm][r] + bv;
            out[(size_t)oc * NPIX + y * 64 + px] = val;
            ps += val;
            ps2 = fmaf(val, val, ps2);
        }
    if (COUT >= 64) {
#pragma unroll
        for (int m = 32; m; m >>= 1) { ps += __shfl_xor(ps, m); ps2 += __shfl_xor(ps2, m); }
        if (lane == 0) {
            if (COUT == 64) {
                pout[wv * NPOUT + y] = make_float2(ps, ps2);
            } else {
                int grp = blockIdx.y * 2 + (wv >> 1);
                pout[grp * NPOUT + y * 2 + (wv & 1)] = make_float2(ps, ps2);
            }
        }
    } else {
#pragma unroll
        for (int m : {1, 2, 16, 32}) { ps += __shfl_xor(ps, m); ps2 += __shfl_xor(ps2, m); }
        int q = (lane >> 2) & 3;
        if (lane == q * 4)
            pout[q * NPOUT + y * 4 + wv] = make_float2(ps, ps2);
    }
}

// ---------------- final GN apply + relu (reads float2 partials) ----------------
__global__ __launch_bounds__(256) void gn_apply_relu(const float* __restrict__ in, const float2* __restrict__ part,
                                                     const float* __restrict__ gamma, const float* __restrict__ beta,
                                                     int Cg, int npart, float* __restrict__ out) {
    int idx4 = blockIdx.x * 256 + threadIdx.x;
    int c = idx4 >> 10;
    int g = c / Cg;
    float s = 0.0f, s2 = 0.0f;
    for (int b = 0; b < npart; b++) {
        float2 p = part[g * npart + b];
        s += p.x; s2 += p.y;
    }
    float n = (float)(Cg * NPIX);
    float mu = s / n;
    float rstd = rsqrtf(s2 / n - mu * mu + 1e-5f);
    float ga = gamma[c] * rstd;
    float be = beta[c] - mu * ga;
    float4 v = ((const float4*)in)[idx4];
    float4 o;
    o.x = fmaf(v.x, ga, be); o.x = o.x > 0.f ? o.x : 0.f;
    o.y = fmaf(v.y, ga, be); o.y = o.y > 0.f ? o.y : 0.f;
    o.z = fmaf(v.z, ga, be); o.z = o.z > 0.f ? o.z : 0.f;
    o.w = fmaf(v.w, ga, be); o.w = o.w > 0.f ? o.w : 0.f;
    ((float4*)out)[idx4] = o;
}

// ---------------- launch ----------------
extern "C" void kernel_launch(void* const* d_in, const int* in_sizes, int n_in,
                              void* d_out, int out_size, void* d_ws, size_t ws_size,
                              hipStream_t stream) {
    const float* x0 = (const float*)d_in[0];
    const float* x1 = (const float*)d_in[1];
    const float* x2 = (const float*)d_in[2];
    const float* x3 = (const float*)d_in[3];
    const float* dox = (const float*)d_in[4];
    const float* wq  = (const float*)d_in[5];
    const float* bq  = (const float*)d_in[6];
    const float* wsm = (const float*)d_in[7];
    const float* bs  = (const float*)d_in[8];
    const float* cw1 = (const float*)d_in[9];
    const float* cb1 = (const float*)d_in[10];
    const float* g1  = (const float*)d_in[11];
    const float* be1 = (const float*)d_in[12];
    const float* cw2 = (const float*)d_in[13];
    const float* cb2 = (const float*)d_in[14];
    const float* g2  = (const float*)d_in[15];
    const float* be2 = (const float*)d_in[16];
    const float* cw3 = (const float*)d_in[17];
    const float* cb3 = (const float*)d_in[18];
    const float* g3  = (const float*)d_in[19];
    const float* be3 = (const float*)d_in[20];

    // u16 region
    uint16_t* Qbf  = (uint16_t*)d_ws;                        // 4194304
    uint16_t* Csbf = Qbf + (size_t)4194304;                  // 2621440
    uint16_t* PS   = Csbf + (size_t)2621440;                 // 2621440
    uint16_t* WB   = PS + (size_t)2621440;                   // 131072
    uint16_t* Wk1  = WB + 131072;                            // 2048
    uint16_t* Wk2  = Wk1 + 2048;                             // 26624
    uint16_t* Wk3  = Wk2 + 26624;                            // 73728
    // float region
    float* fbase  = (float*)(Wk3 + 73728);
    float* mexpb  = fbase;                 // 10240
    float* inv    = mexpb + 10240;         // 10240
    float* sfbuf  = inv + 10240;           // 4sc*8split*2*8*4096 = 2097152
    float* cm     = sfbuf + 2097152;       // 16384
    float* h1     = cm + 16384;            // 65536
    float* h2     = h1 + 65536;            // 262144
    float* h3     = h2 + 262144;           // 524288
    float2* part1 = (float2*)(h3 + 524288);   // 4*256 f2
    float2* part2 = part1 + 4 * 256;          // 4*64 f2
    float2* part3 = part2 + 4 * 64;           // 4*128 f2

    // prepack
    prep_all<<<(233472 + 255) / 256, 256, 0, stream>>>(wq, wsm, cw1, cw2, cw3, WB, Wk1, Wk2, Wk3);

    // pipeline
    patch_sum<<<dim3(16, 4, 20), 256, 0, stream>>>(x0, x1, x2, x3, dox, PS, inv, mexpb);
    q_gemm<<<dim3(64, 4), 512, 0, stream>>>(x0, x1, x2, x3, WB, bq, Qbf);
    cent_gemm<<<dim3(80, 4), 256, 0, stream>>>(PS, WB, bs, inv, Csbf);
    attn_v8<<<dim3(16, NH, 32), 256, 0, stream>>>(Qbf, Csbf, mexpb, sfbuf);
    mean_heads4<<<64, 256, 0, stream>>>(sfbuf, cm);

    // conv tail with fused GN
    conv_mfma<4, 16, 5, 1, 256, false><<<dim3(64, 1), 256, 0, stream>>>(
        cm, Wk1, cb1, nullptr, nullptr, nullptr, h1, part1);
    conv_mfma<16, 64, 5, 256, 64, true><<<dim3(64, 1), 256, 0, stream>>>(
        h1, Wk2, cb2, g1, be1, part1, h2, part2);
    conv_mfma<64, 128, 3, 64, 128, true><<<dim3(64, 2), 256, 0, stream>>>(
        h2, Wk3, cb3, g2, be2, part2, h3, part3);
    gn_apply_relu<<<(128 * 1024) / 256, 256, 0, stream>>>(h3, part3, g3, be3, 32, 128, (float*)d_out);
}

// Round 18
// 144.573 us; speedup vs baseline: 1.1319x; 1.0349x over previous
//
#include <hip/hip_runtime.h>
#include <hip/hip_bf16.h>
#include <stdint.h>

#define CCH 256
#define NPIX 4096      // 64*64
#define NH 8
#define M2 2560        // K*2*S
#define LOG2E 1.44269504088896f

typedef __attribute__((ext_vector_type(8))) short short8;
typedef __attribute__((ext_vector_type(4))) float f32x4;

__device__ __forceinline__ uint16_t f2bfu(float f) {
    uint32_t u = __builtin_bit_cast(uint32_t, f);
    return (uint16_t)((u + 0x7FFFu + ((u >> 16) & 1u)) >> 16);   // RNE
}
__device__ __forceinline__ uint32_t pack_bf2(float a, float b) {
    return (uint32_t)f2bfu(a) | ((uint32_t)f2bfu(b) << 16);
}
__device__ __forceinline__ short8 u4_to_s8(uint4 v) {
    return __builtin_bit_cast(short8, v);
}

// ---------------- fused prepack: WB (feature weights) + conv Wk1/Wk2/Wk3 ----------------
__device__ __forceinline__ void prep_w_one(const float* __restrict__ w, uint16_t* __restrict__ Wk,
                                           int idx, int Cin, int Cout, int K2) {
    int kk = idx & 31;
    int oc = (idx >> 5) % Cout;
    int ck = idx / (32 * Cout);
    int k = ck * 32 + kk;
    int tap = k / Cin, ic = k % Cin;
    float v = (tap < K2) ? w[((size_t)oc * Cin + ic) * K2 + tap] : 0.0f;
    Wk[idx] = f2bfu(v);
}

__global__ void prep_all(const float* __restrict__ wq, const float* __restrict__ wsm,
                         const float* __restrict__ cw1, const float* __restrict__ cw2,
                         const float* __restrict__ cw3,
                         uint16_t* __restrict__ WB, uint16_t* __restrict__ Wk1,
                         uint16_t* __restrict__ Wk2, uint16_t* __restrict__ Wk3) {
    int idx = blockIdx.x * 256 + threadIdx.x;
    if (idx < 131072) {
        const float* src = (idx < 65536) ? wq : wsm;
        WB[idx] = f2bfu(src[idx & 65535]);
        return;
    }
    idx -= 131072;
    if (idx < 2048)  { prep_w_one(cw1, Wk1, idx, 4, 16, 25);  return; }
    idx -= 2048;
    if (idx < 26624) { prep_w_one(cw2, Wk2, idx, 16, 64, 25); return; }
    idx -= 26624;
    if (idx < 73728) { prep_w_one(cw3, Wk3, idx, 64, 128, 9); return; }
}

// ---------------- patch-weighted sums of x (linearity: centroids = W.psum/fgs + b) ----------
__global__ __launch_bounds__(256) void patch_sum(
        const float* __restrict__ x0, const float* __restrict__ x1,
        const float* __restrict__ x2, const float* __restrict__ x3,
        const float* __restrict__ dox, uint16_t* __restrict__ PS,
        float* __restrict__ inv, float* __restrict__ mexpb) {
    int z = blockIdx.z;
    int sc = z / 5, k = z % 5;
    const float* xim = ((sc == 0) ? x0 : (sc == 1) ? x1 : (sc == 2) ? x2 : x3)
                       + (size_t)(k + 1) * CCH * NPIX;
    int p1 = blockIdx.x, chq = blockIdx.y;
    int tid = threadIdx.x;
    int cloc = tid >> 6, col = tid & 63;
    __shared__ float wls[4][64];
    __shared__ uint16_t pst[2][16][72];
    wls[cloc][col] = dox[(size_t)k * 65536 + (size_t)(16 * p1 + 4 * cloc) * 256 + 4 * col];
    __syncthreads();
    float w0 = wls[0][col], w1 = wls[1][col], w2 = wls[2][col], w3 = wls[3][col];
    const float* xbase = xim + p1 * 256 + col;
#pragma unroll 4
    for (int it = 0; it < 16; ++it) {
        int c = chq * 64 + it * 4 + cloc;
        const float* xp = xbase + (size_t)c * NPIX;
        float v0 = xp[0], v1 = xp[64], v2 = xp[128], v3 = xp[192];
        float pf = w0 * v0 + w1 * v1 + w2 * v2 + w3 * v3;
        float pb = (v0 + v1 + v2 + v3) - pf;
        pf += __shfl_xor(pf, 1); pf += __shfl_xor(pf, 2);
        pb += __shfl_xor(pb, 1); pb += __shfl_xor(pb, 2);
        if ((col & 3) == 0) {
            int q = col >> 2, cl = it * 4 + cloc;
            pst[0][q][cl] = f2bfu(pf);
            pst[1][q][cl] = f2bfu(pb);
        }
    }
    if (chq == 0 && tid < 64) {
        float ws = w0 + w1 + w2 + w3;
        ws += __shfl_xor(ws, 1); ws += __shfl_xor(ws, 2);
        if ((col & 3) == 0) {
            int s = p1 * 16 + (col >> 2);
            float fsum = ws, bsum = 16.f - ws;
            int mf = k * 512 + s, mbk = mf + 256;
            mexpb[sc * M2 + mf]  = (fsum < 1.f) ? 0.f : 1.f;
            mexpb[sc * M2 + mbk] = (bsum < 1.f) ? 0.f : 1.f;
            inv[(size_t)(z * 2 + 0) * 256 + s] = 1.f / fmaxf(fsum, 1e-6f);
            inv[(size_t)(z * 2 + 1) * 256 + s] = 1.f / fmaxf(bsum, 1e-6f);
        }
    }
    __syncthreads();
    int fb = tid >> 7, rem = tid & 127;
    int q = rem >> 3, chunk = rem & 7;
    uint4 v = *(const uint4*)&pst[fb][q][chunk * 8];
    int s = p1 * 16 + q;
    *(uint4*)&PS[((size_t)(z * 2 + fb) * 256 + s) * CCH + chq * 64 + chunk * 8] = v;
}

// ---------------- centroid GEMM: Cs = W.(psum)*inv + b ----------------
__global__ __launch_bounds__(256) void cent_gemm(
        const uint16_t* __restrict__ PS, const uint16_t* __restrict__ WB,
        const float* __restrict__ bs, const float* __restrict__ inv,
        uint16_t* __restrict__ Csbf) {
    int tid = threadIdx.x, lane = tid & 63, wid = tid >> 6;
    int lp = lane & 15, g = lane >> 4;
    int rowb = blockIdx.x * 128 + wid * 32;
    int cob = blockIdx.y * 64;
    const uint16_t* wsb = WB + 65536;
    f32x4 acc[2][4] = {};
#pragma unroll
    for (int ks = 0; ks < 8; ++ks) {
        int k0 = ks * 32;
        uint4 a0 = *(const uint4*)(PS + (size_t)(rowb + lp) * CCH + k0 + g * 8);
        uint4 a1 = *(const uint4*)(PS + (size_t)(rowb + 16 + lp) * CCH + k0 + g * 8);
        short8 af[2] = {u4_to_s8(a0), u4_to_s8(a1)};
        short8 b[4];
#pragma unroll
        for (int t = 0; t < 4; ++t) {
            uint4 bw = *(const uint4*)(wsb + (size_t)(cob + t * 16 + lp) * 256 + k0 + g * 8);
            b[t] = u4_to_s8(bw);
        }
#pragma unroll
        for (int m = 0; m < 2; ++m)
#pragma unroll
            for (int t = 0; t < 4; ++t)
                acc[m][t] = __builtin_amdgcn_mfma_f32_16x16x32_bf16(af[m], b[t], acc[m][t], 0, 0, 0);
    }
#pragma unroll
    for (int m = 0; m < 2; ++m)
#pragma unroll
        for (int t = 0; t < 4; ++t) {
            int co = cob + t * 16 + lp;
            int h = co >> 5, d = co & 31;
            float bv = bs[co];
#pragma unroll
            for (int r = 0; r < 4; ++r) {
                int row = rowb + m * 16 + g * 4 + r;
                int zz = row >> 9, fb = (row >> 8) & 1, s = row & 255;
                int scc = zz / 5, kk = zz % 5;
                int slot = kk * 512 + fb * 256 + s;
                float val = acc[m][t][r] * inv[row] + bv;
                Csbf[(((size_t)scc * NH + h) * M2 + slot) * 32 + d] = f2bfu(val);
            }
        }
}

// ---------------- Q GEMM (img 0 only) ----------------
__global__ __launch_bounds__(512) void q_gemm(
        const float* __restrict__ x0, const float* __restrict__ x1,
        const float* __restrict__ x2, const float* __restrict__ x3,
        const uint16_t* __restrict__ WB, const float* __restrict__ bq,
        uint16_t* __restrict__ Qbf) {
    int sc = blockIdx.y;
    const float* xim = (sc == 0) ? x0 : (sc == 1) ? x1 : (sc == 2) ? x2 : x3;
    int p0 = blockIdx.x * 64;
    int tid = threadIdx.x, lane = tid & 63, wid = tid >> 6;
    int lp = lane & 15, g = lane >> 4;
    int wm = wid >> 1, wn = wid & 1;
    __shared__ uint32_t Al[16][68];
    f32x4 acc[8] = {};
#pragma unroll
    for (int ks = 0; ks < 8; ++ks) {
        int k0 = ks * 32;
        __syncthreads();
        if (tid < 256) {
            int rp = tid >> 4, f4i = tid & 15;
            float4 v0 = *(const float4*)(xim + (size_t)(k0 + 2 * rp) * NPIX + p0 + f4i * 4);
            float4 v1 = *(const float4*)(xim + (size_t)(k0 + 2 * rp + 1) * NPIX + p0 + f4i * 4);
            *(uint4*)&Al[rp][f4i * 4] = make_uint4(
                pack_bf2(v0.x, v1.x), pack_bf2(v0.y, v1.y),
                pack_bf2(v0.z, v1.z), pack_bf2(v0.w, v1.w));
        }
        __syncthreads();
        short8 b[8];
#pragma unroll
        for (int tn = 0; tn < 8; ++tn) {
            uint4 bw = *(const uint4*)(WB + (size_t)(wn * 128 + tn * 16 + lp) * 256 + k0 + g * 8);
            b[tn] = u4_to_s8(bw);
        }
        int px = wm * 16 + lp;
        uint4 av = make_uint4(Al[4 * g + 0][px], Al[4 * g + 1][px],
                              Al[4 * g + 2][px], Al[4 * g + 3][px]);
        short8 af = u4_to_s8(av);
#pragma unroll
        for (int tn = 0; tn < 8; ++tn)
            acc[tn] = __builtin_amdgcn_mfma_f32_16x16x32_bf16(af, b[tn], acc[tn], 0, 0, 0);
    }
#pragma unroll
    for (int tn = 0; tn < 8; ++tn) {
        int co = wn * 128 + tn * 16 + lp;
        float bv = bq[co];
#pragma unroll
        for (int r = 0; r < 4; ++r) {
            int row = p0 + wm * 16 + g * 4 + r;
            Qbf[((size_t)(sc * NPIX + row)) * CCH + co] = f2bfu((acc[tn][r] + bv) * LOG2E);
        }
    }
}

// ---------------- attention v6: multiplicative mask, zero C-init, B-frags from L2 ----------
__global__ __launch_bounds__(256) void attn_v6(
        const uint16_t* __restrict__ Qbf, const uint16_t* __restrict__ Csbf,
        const float* __restrict__ mexpb, float* __restrict__ sfbuf) {
    int head = blockIdx.y;
    int sc = blockIdx.z >> 2, split = blockIdx.z & 3;
    int tid = threadIdx.x;
    int lane = tid & 63, wid = tid >> 6;
    int lp = lane & 15, g = lane >> 4;
    int p0w = blockIdx.x * 256 + wid * 64;

    const uint16_t* Qs = Qbf + (size_t)sc * NPIX * CCH;
    const uint16_t* csb = Csbf + ((size_t)sc * NH + head) * M2 * 32;
    const float* mb = mexpb + sc * M2;

    short8 aq[4];
#pragma unroll
    for (int m = 0; m < 4; m++) {
        uint4 qv = *(const uint4*)(Qs + (size_t)(p0w + m * 16 + lp) * CCH + head * 32 + g * 8);
        aq[m] = u4_to_s8(qv);
    }

    const f32x4 zero4 = {0.f, 0.f, 0.f, 0.f};
    float sfg[4][4] = {}, sbg[4][4] = {};
    int cbeg = split * 640;
    for (int c0loc = 0; c0loc < 640; c0loc += 64) {
        int c0 = cbeg + c0loc;
        bool fg = ((c0 & 511) < 256);
        short8 bf[4];
        float mexp[4];
#pragma unroll
        for (int t = 0; t < 4; t++) {
            int row = c0 + t * 16 + lp;
            bf[t] = u4_to_s8(*(const uint4*)(csb + (size_t)row * 32 + g * 8));
            mexp[t] = mb[row];
        }
        if (fg) {
#pragma unroll
            for (int m = 0; m < 4; m++)
#pragma unroll
                for (int t = 0; t < 4; t++) {
                    f32x4 c = __builtin_amdgcn_mfma_f32_16x16x32_bf16(aq[m], bf[t], zero4, 0, 0, 0);
#pragma unroll
                    for (int r = 0; r < 4; r++)
                        sfg[m][r] = fmaf(__builtin_amdgcn_exp2f(c[r]), mexp[t], sfg[m][r]);
                }
        } else {
#pragma unroll
            for (int m = 0; m < 4; m++)
#pragma unroll
                for (int t = 0; t < 4; t++) {
                    f32x4 c = __builtin_amdgcn_mfma_f32_16x16x32_bf16(aq[m], bf[t], zero4, 0, 0, 0);
#pragma unroll
                    for (int r = 0; r < 4; r++)
                        sbg[m][r] = fmaf(__builtin_amdgcn_exp2f(c[r]), mexp[t], sbg[m][r]);
                }
        }
    }
#pragma unroll
    for (int m = 0; m < 4; m++)
#pragma unroll
        for (int r = 0; r < 4; r++) {
#pragma unroll
            for (int msk = 1; msk < 16; msk <<= 1) {
                sfg[m][r] += __shfl_xor(sfg[m][r], msk);
                sbg[m][r] += __shfl_xor(sbg[m][r], msk);
            }
        }
    if (lp == 0) {
        float* sf = sfbuf + (size_t)((sc * 4 + split) * 2) * NH * NPIX;
        float* so = sf + (size_t)head * NPIX;
        float* fo = sf + (size_t)(NH + head) * NPIX;
#pragma unroll
        for (int m = 0; m < 4; m++)
#pragma unroll
            for (int r = 0; r < 4; r++) {
                int px = p0w + m * 16 + g * 4 + r;
                so[px] = sfg[m][r] + sbg[m][r];
                fo[px] = sfg[m][r];
            }
    }
}

// ---------------- head mean over 4 split partials ----------------
__global__ void mean_heads3(const float* __restrict__ sfbuf, float* __restrict__ cm) {
    int idx = blockIdx.x * 256 + threadIdx.x;
    int sc = idx >> 12, p = idx & 4095;
    const float* b = sfbuf + (size_t)sc * 4 * 2 * NH * NPIX;
    float acc = 0.f;
#pragma unroll
    for (int h = 0; h < NH; h++) {
        float sv = 0.f, fv = 0.f;
#pragma unroll
        for (int sp = 0; sp < 4; sp++) {
            sv += b[((size_t)(sp * 2) * NH + h) * NPIX + p];
            fv += b[((size_t)(sp * 2 + 1) * NH + h) * NPIX + p];
        }
        acc += fv / sv;
    }
    cm[idx] = 0.125f * acc;
}

// ---------------- implicit-GEMM conv + fused GN(on-load) + GN-partials (epilogue) --------
template<int CIN, int COUT, int KSZ, int NPIN, int NPOUT, bool GNIN>
__global__ __launch_bounds__(256) void conv_mfma(
        const float* __restrict__ in, const uint16_t* __restrict__ Wk,
        const float* __restrict__ bias,
        const float* __restrict__ gin, const float* __restrict__ bein,
        const float2* __restrict__ pin,
        float* __restrict__ out, float2* __restrict__ pout) {
    constexpr int PAD = KSZ / 2;
    constexpr int NTAP = KSZ * KSZ;
    constexpr int K = CIN * NTAP;
    constexpr int CK = (K + 31) / 32;
    constexpr int PXP = 64 + 2 * PAD;
    constexpr int ICB = (CIN >= 8) ? CIN / 8 : 1;
    __shared__ uint16_t Xs[KSZ * PXP * CIN];
    __shared__ float gaL[CIN], beL[CIN];
    __shared__ float gmu[4], grs[4];
    int tid = threadIdx.x;
    int lane = tid & 63, wv = tid >> 6;
    int lp = lane & 15, g = lane >> 4;
    int y = blockIdx.x;
    int oc0 = blockIdx.y * 64;

    if (GNIN) {
        float s = 0.f, s2 = 0.f;
        for (int i = lane; i < NPIN; i += 64) {
            float2 p = pin[wv * NPIN + i];
            s += p.x; s2 += p.y;
        }
#pragma unroll
        for (int m = 32; m; m >>= 1) { s += __shfl_xor(s, m); s2 += __shfl_xor(s2, m); }
        if (lane == 0) {
            float n = (float)((CIN / 4) * NPIX);
            float mu = s / n;
            gmu[wv] = mu;
            grs[wv] = rsqrtf(s2 / n - mu * mu + 1e-5f);
        }
        __syncthreads();
        if (tid < CIN) {
            int gg = tid / (CIN / 4);
            float ga = gin[tid] * grs[gg];
            gaL[tid] = ga;
            beL[tid] = bein[tid] - gmu[gg] * ga;
        }
        __syncthreads();
    }

    if (CIN >= 8) {
        for (int idx = tid; idx < KSZ * ICB * PXP; idx += 256) {
            int pxp = idx % PXP; int rem = idx / PXP;
            int icb = rem % ICB; int r = rem / ICB;
            int gy = y + r - PAD, gx = pxp - PAD;
            bool ok = ((unsigned)gy < 64u) && ((unsigned)gx < 64u);
            const float* ip = in + (size_t)(icb * 8) * NPIX + gy * 64 + gx;
            uint32_t wb[4];
#pragma unroll
            for (int j = 0; j < 4; j++) {
                int c0c = icb * 8 + 2 * j, c1c = c0c + 1;
                float v0 = ok ? ip[(size_t)(2 * j) * NPIX] : 0.f;
                float v1 = ok ? ip[(size_t)(2 * j + 1) * NPIX] : 0.f;
                if (GNIN) {
                    v0 = fmaf(v0, gaL[c0c], beL[c0c]); v0 = v0 > 0.f ? v0 : 0.f;
                    v1 = fmaf(v1, gaL[c1c], beL[c1c]); v1 = v1 > 0.f ? v1 : 0.f;
                    if (!ok) { v0 = 0.f; v1 = 0.f; }
                }
                wb[j] = pack_bf2(v0, v1);
            }
            *(uint4*)&Xs[(size_t)idx * 8] = make_uint4(wb[0], wb[1], wb[2], wb[3]);
        }
    } else {
        for (int idx = tid; idx < KSZ * PXP; idx += 256) {
            int pxp = idx % PXP; int r = idx / PXP;
            int gy = y + r - PAD, gx = pxp - PAD;
            bool ok = ((unsigned)gy < 64u) && ((unsigned)gx < 64u);
            const float* ip = in + (size_t)gy * 64 + gx;
            float v0 = ok ? ip[0] : 0.f, v1 = ok ? ip[NPIX] : 0.f;
            float v2 = ok ? ip[2 * NPIX] : 0.f, v3 = ok ? ip[3 * NPIX] : 0.f;
            *(uint2*)&Xs[(size_t)idx * 4] = make_uint2(pack_bf2(v0, v1), pack_bf2(v2, v3));
        }
    }
    __syncthreads();

    int tmb, tme, tn;
    if (COUT >= 64) { tn = wv; tmb = 0; tme = 4; }
    else            { tn = 0;  tmb = wv; tme = wv + 1; }
    int oc = oc0 + tn * 16 + lp;
    f32x4 acc[4] = {};

#pragma unroll
    for (int ck = 0; ck < CK; ck++) {
        const uint16_t* wp = Wk + ((size_t)ck * COUT + oc) * 32 + g * 8;
        uint4 bw = *(const uint4*)wp;
        short8 bfr = u4_to_s8(bw);
        if (CIN >= 8) {
            int gk = ck * 4 + g;
            int tap = gk / ICB; if (tap > NTAP - 1) tap = NTAP - 1;
            int icb = gk % ICB;
            int r = tap / KSZ, dx = tap % KSZ;
            int base = (r * ICB + icb) * PXP * 8;
            for (int tm = tmb; tm < tme; tm++) {
                int pxp = tm * 16 + lp + dx;
                uint4 av = *(const uint4*)&Xs[base + pxp * 8];
                short8 afr = u4_to_s8(av);
                acc[tm] = __builtin_amdgcn_mfma_f32_16x16x32_bf16(afr, bfr, acc[tm], 0, 0, 0);
            }
        } else {
            int gk = ck * 4 + g;
            int t0 = 2 * gk;     if (t0 > NTAP - 1) t0 = NTAP - 1;
            int t1 = 2 * gk + 1; if (t1 > NTAP - 1) t1 = NTAP - 1;
            int r0 = t0 / KSZ, dx0 = t0 % KSZ;
            int r1 = t1 / KSZ, dx1 = t1 % KSZ;
            for (int tm = tmb; tm < tme; tm++) {
                uint2 a0 = *(const uint2*)&Xs[((size_t)(r0 * PXP + tm * 16 + lp + dx0)) * 4];
                uint2 a1 = *(const uint2*)&Xs[((size_t)(r1 * PXP + tm * 16 + lp + dx1)) * 4];
                uint4 av = make_uint4(a0.x, a0.y, a1.x, a1.y);
                short8 afr = u4_to_s8(av);
                acc[tm] = __builtin_amdgcn_mfma_f32_16x16x32_bf16(afr, bfr, acc[tm], 0, 0, 0);
            }
        }
    }
    float bv = bias[oc];
    float ps = 0.f, ps2 = 0.f;
    for (int tm = tmb; tm < tme; tm++)
#pragma unroll
        for (int r = 0; r < 4; r++) {
            int px = tm * 16 + g * 4 + r;
            float val = acc[tm][r] + bv;
            out[(size_t)oc * NPIX + y * 64 + px] = val;
            ps += val;
            ps2 = fmaf(val, val, ps2);
        }
    if (COUT >= 64) {
#pragma unroll
        for (int m = 32; m; m >>= 1) { ps += __shfl_xor(ps, m); ps2 += __shfl_xor(ps2, m); }
        if (lane == 0) {
            if (COUT == 64) {
                pout[wv * NPOUT + y] = make_float2(ps, ps2);
            } else {
                int grp = blockIdx.y * 2 + (wv >> 1);
                pout[grp * NPOUT + y * 2 + (wv & 1)] = make_float2(ps, ps2);
            }
        }
    } else {
#pragma unroll
        for (int m : {1, 2, 16, 32}) { ps += __shfl_xor(ps, m); ps2 += __shfl_xor(ps2, m); }
        int q = (lane >> 2) & 3;
        if (lane == q * 4)
            pout[q * NPOUT + y * 4 + wv] = make_float2(ps, ps2);
    }
}

// ---------------- final GN apply + relu (reads float2 partials) ----------------
__global__ __launch_bounds__(256) void gn_apply_relu(const float* __restrict__ in, const float2* __restrict__ part,
                                                     const float* __restrict__ gamma, const float* __restrict__ beta,
                                                     int Cg, int npart, float* __restrict__ out) {
    int idx4 = blockIdx.x * 256 + threadIdx.x;
    int c = idx4 >> 10;
    int g = c / Cg;
    float s = 0.0f, s2 = 0.0f;
    for (int b = 0; b < npart; b++) {
        float2 p = part[g * npart + b];
        s += p.x; s2 += p.y;
    }
    float n = (float)(Cg * NPIX);
    float mu = s / n;
    float rstd = rsqrtf(s2 / n - mu * mu + 1e-5f);
    float ga = gamma[c] * rstd;
    float be = beta[c] - mu * ga;
    float4 v = ((const float4*)in)[idx4];
    float4 o;
    o.x = fmaf(v.x, ga, be); o.x = o.x > 0.f ? o.x : 0.f;
    o.y = fmaf(v.y, ga, be); o.y = o.y > 0.f ? o.y : 0.f;
    o.z = fmaf(v.z, ga, be); o.z = o.z > 0.f ? o.z : 0.f;
    o.w = fmaf(v.w, ga, be); o.w = o.w > 0.f ? o.w : 0.f;
    ((float4*)out)[idx4] = o;
}

// ---------------- launch ----------------
extern "C" void kernel_launch(void* const* d_in, const int* in_sizes, int n_in,
                              void* d_out, int out_size, void* d_ws, size_t ws_size,
                              hipStream_t stream) {
    const float* x0 = (const float*)d_in[0];
    const float* x1 = (const float*)d_in[1];
    const float* x2 = (const float*)d_in[2];
    const float* x3 = (const float*)d_in[3];
    const float* dox = (const float*)d_in[4];
    const float* wq  = (const float*)d_in[5];
    const float* bq  = (const float*)d_in[6];
    const float* wsm = (const float*)d_in[7];
    const float* bs  = (const float*)d_in[8];
    const float* cw1 = (const float*)d_in[9];
    const float* cb1 = (const float*)d_in[10];
    const float* g1  = (const float*)d_in[11];
    const float* be1 = (const float*)d_in[12];
    const float* cw2 = (const float*)d_in[13];
    const float* cb2 = (const float*)d_in[14];
    const float* g2  = (const float*)d_in[15];
    const float* be2 = (const float*)d_in[16];
    const float* cw3 = (const float*)d_in[17];
    const float* cb3 = (const float*)d_in[18];
    const float* g3  = (const float*)d_in[19];
    const float* be3 = (const float*)d_in[20];

    // u16 region
    uint16_t* Qbf  = (uint16_t*)d_ws;                        // 4194304
    uint16_t* Csbf = Qbf + (size_t)4194304;                  // 2621440
    uint16_t* PS   = Csbf + (size_t)2621440;                 // 2621440
    uint16_t* WB   = PS + (size_t)2621440;                   // 131072
    uint16_t* Wk1  = WB + 131072;                            // 2048
    uint16_t* Wk2  = Wk1 + 2048;                             // 26624
    uint16_t* Wk3  = Wk2 + 26624;                            // 73728
    // float region
    float* fbase  = (float*)(Wk3 + 73728);
    float* mexpb  = fbase;                 // 10240
    float* inv    = mexpb + 10240;         // 10240
    float* sfbuf  = inv + 10240;           // 1048576
    float* cm     = sfbuf + 1048576;       // 16384
    float* h1     = cm + 16384;            // 65536
    float* h2     = h1 + 65536;            // 262144
    float* h3     = h2 + 262144;           // 524288
    float2* part1 = (float2*)(h3 + 524288);   // 4*256 f2
    float2* part2 = part1 + 4 * 256;          // 4*64 f2
    float2* part3 = part2 + 4 * 64;           // 4*128 f2

    // fused prepack (WB + Wk1..3)
    prep_all<<<(233472 + 255) / 256, 256, 0, stream>>>(wq, wsm, cw1, cw2, cw3, WB, Wk1, Wk2, Wk3);

    // pipeline
    patch_sum<<<dim3(16, 4, 20), 256, 0, stream>>>(x0, x1, x2, x3, dox, PS, inv, mexpb);
    q_gemm<<<dim3(64, 4), 512, 0, stream>>>(x0, x1, x2, x3, WB, bq, Qbf);
    cent_gemm<<<dim3(80, 4), 256, 0, stream>>>(PS, WB, bs, inv, Csbf);
    attn_v6<<<dim3(16, NH, 16), 256, 0, stream>>>(Qbf, Csbf, mexpb, sfbuf);
    mean_heads3<<<64, 256, 0, stream>>>(sfbuf, cm);

    // conv tail with fused GN
    conv_mfma<4, 16, 5, 1, 256, false><<<dim3(64, 1), 256, 0, stream>>>(
        cm, Wk1, cb1, nullptr, nullptr, nullptr, h1, part1);
    conv_mfma<16, 64, 5, 256, 64, true><<<dim3(64, 1), 256, 0, stream>>>(
        h1, Wk2, cb2, g1, be1, part1, h2, part2);
    conv_mfma<64, 128, 3, 64, 128, true><<<dim3(64, 2), 256, 0, stream>>>(
        h2, Wk3, cb3, g2, be2, part2, h3, part3);
    gn_apply_relu<<<(128 * 1024) / 256, 256, 0, stream>>>(h3, part3, g3, be3, 32, 128, (float*)d_out);
}